// Round 4
// baseline (86.735 us; speedup 1.0000x reference)
//
#include <hip/hip_runtime.h>
#include <hip/hip_bf16.h>
#include <stdint.h>

// out[b,j] = sum_{i,k} softmax(alphas[i,j,:])[k] * coeffs[i,j,k] * prim_k(x[b,i])
//         == P @ W2,  P[b, kg] = prim_op(x[b,i]),  W2[kg][j]
// k-ordering remapped so the MFMA A-fragment is one cacheline/lane:
//   kg = c*32 + quad*8 + j  <->  i = quad*16 + c , op = j   (c=0..15, quad=0..3)
//
// R4 design: NO LDS, NO barriers.
//  - build_w writes W2 in B-fragment order to d_ws (64 KB, L2-hot).
//  - main: 4096 blocks x 256 thr. Block = rows blk*16..+15, all 64 cols.
//    Wave w = col-tile w (16 cols). B-fragments live in REGISTERS:
//    16 x bf16x8 = 64 VGPR, loaded as 16 coalesced 1KB/wave global reads.
//  - A-side: lane (m,q) holds x[row m][16q..16q+15] in regs; prims on the fly.
//  - C/D layout: col=lane&15, row=quad*4+reg (m89-verified).
// Waves free-run; latency hidden by 16 waves/CU (launch_bounds(256,4)).

typedef __bf16 bf16x8 __attribute__((ext_vector_type(8)));
typedef float f32x4 __attribute__((ext_vector_type(4)));

// ---------------- kernel 1: build W2 in MFMA B-fragment order (bf16) --------
__global__ void build_w(const float* __restrict__ alphas,
                        const float* __restrict__ coeffs,
                        __bf16* __restrict__ w2) {
    int gid = blockIdx.x * blockDim.x + threadIdx.x;   // 0..4095 == i*64 + n
    int i = gid >> 6;
    int n = gid & 63;
    const float* a = alphas + gid * 8;
    const float* c = coeffs + gid * 8;

    float av[8], mx = -1e30f;
#pragma unroll
    for (int k = 0; k < 8; ++k) { av[k] = a[k]; mx = fmaxf(mx, av[k]); }
    float e[8], s = 0.f;
#pragma unroll
    for (int k = 0; k < 8; ++k) { e[k] = __expf(av[k] - mx); s += e[k]; }
    float inv = 1.0f / s;

    bf16x8 w;
#pragma unroll
    for (int k = 0; k < 8; ++k) w[k] = (__bf16)(e[k] * inv * c[k]);

    // i = q*16 + cc (q = k-quad, cc = step); n = t*16 + nl
    int q = i >> 4, cc = i & 15, t = n >> 4, nl = n & 15;
    int pos = ((cc * 4 + t) * 64 + q * 16 + nl) * 8;
    *(bf16x8*)(w2 + pos) = w;    // 16B store
}

// ---------------- kernel 2: main GEMM, no LDS / no barriers ----------------
__global__ __launch_bounds__(256, 4) void darts_main(const float* __restrict__ x,
                                                     const __bf16* __restrict__ w2,
                                                     float* __restrict__ out) {
    const int tid  = threadIdx.x;
    const int lane = tid & 63;
    const int wv   = tid >> 6;       // 0..3 == col-tile
    const int m    = lane & 15;      // A row within 16-tile / C col within 16-tile
    const int q    = lane >> 4;      // quad

    // x: one 64B line per lane, straight to registers (coalesced in aggregate)
    const int row = blockIdx.x * 16 + m;
    const float* xp = x + row * 64 + q * 16;
    f32x4 xr0 = *(const f32x4*)(xp + 0);
    f32x4 xr1 = *(const f32x4*)(xp + 4);
    f32x4 xr2 = *(const f32x4*)(xp + 8);
    f32x4 xr3 = *(const f32x4*)(xp + 12);

    // B-fragments for this wave's col-tile: 16 steps x 16B/lane, each a
    // contiguous 1KB/wave read of L2-hot w2.
    bf16x8 bf[16];
#pragma unroll
    for (int c = 0; c < 16; ++c) {
        bf[c] = *(const bf16x8*)(w2 + ((c * 4 + wv) * 64 + lane) * 8);
    }

    float xa[16];
#pragma unroll
    for (int c = 0; c < 4; ++c) { xa[c] = xr0[c]; xa[4+c] = xr1[c]; xa[8+c] = xr2[c]; xa[12+c] = xr3[c]; }

    f32x4 acc = {0.f, 0.f, 0.f, 0.f};

#pragma unroll
    for (int c = 0; c < 16; ++c) {
        const float xv = xa[c];
        const float x2 = xv * xv;
        bf16x8 a;
        a[0] = (__bf16)0.0f;                      // 'none'
        a[1] = (__bf16)xv;                        // linear
        a[2] = (__bf16)x2;                        // x^2
        a[3] = (__bf16)(x2 * xv);                 // x^3
        a[4] = (__bf16)__expf(xv);                // exp
        a[5] = (__bf16)__logf(xv);                // ln
        a[6] = (__bf16)__builtin_amdgcn_rcpf(xv); // 1/x
        a[7] = (__bf16)__sinf(xv);                // sin
        acc = __builtin_amdgcn_mfma_f32_16x16x32_bf16(a, bf[c], acc, 0, 0, 0);
    }

    // epilogue: C layout col=lane&15 (-> out col wv*16+m), row=q*4+r
    float* orow = out + (blockIdx.x * 16 + q * 4) * 64 + wv * 16 + m;
#pragma unroll
    for (int r = 0; r < 4; ++r) {
        orow[r * 64] = acc[r];
    }
}

extern "C" void kernel_launch(void* const* d_in, const int* in_sizes, int n_in,
                              void* d_out, int out_size, void* d_ws, size_t ws_size,
                              hipStream_t stream) {
    const float* x      = (const float*)d_in[0];
    const float* alphas = (const float*)d_in[1];
    const float* coeffs = (const float*)d_in[2];
    float* out = (float*)d_out;
    __bf16* w2 = (__bf16*)d_ws;   // 32768 bf16 = 64 KB of the workspace

    build_w<<<16, 256, 0, stream>>>(alphas, coeffs, w2);
    darts_main<<<4096, 256, 0, stream>>>(x, w2, out);
}

// Round 5
// 77.136 us; speedup vs baseline: 1.1245x; 1.1245x over previous
//
#include <hip/hip_runtime.h>
#include <hip/hip_bf16.h>
#include <stdint.h>

// out[b,j] = sum_{i,k} softmax(alphas[i,j,:])[k] * coeffs[i,j,k] * prim_k(x[b,i])
//         == P @ W2,  P[b, kg] = prim_op(x[b,i]),  W2[kg][j]
// k-ordering remapped so the MFMA A-fragment is one cacheline/lane:
//   kg = c*32 + quad*8 + j  <->  i = quad*16 + c , op = j   (c=0..15, quad=0..3)
//
// R5: ONE kernel, 256 blocks x 1024 threads (1 block/CU, 16 waves).
//  - Each block: 256 rows; wave w: rows w*16..w*16+15, all 64 cols.
//  - W2 built per block into LDS (B-fragment order); redundancy = 256 x 262KB
//    = 67 MB L2 traffic (half of R3). Softmax max-sub skipped (|alphas|<0.03).
//  - HW transcendentals: v_exp_f32 / v_log_f32 / v_sin_f32 / v_rcp_f32.
//    x in (0.5,1.5) -> no range reduction needed; err << bf16 rounding.
//  - A-side prims in registers (lane (m,q) owns x[row m][16q..16q+15]).
//  - B reads: wlds + c*2048 + t*512 + lane*8 -> contiguous 1KB/wave
//    ds_read_b128, conflict-free.  C/D: col=lane&15, row=quad*4+reg.

typedef __bf16 bf16x8 __attribute__((ext_vector_type(8)));
typedef float f32x4 __attribute__((ext_vector_type(4)));

#define LOG2E   1.4426950408889634f
#define LN2     0.6931471805599453f
#define INV2PI  0.15915494309189535f

__global__ __launch_bounds__(1024, 4) void darts_fused(const float* __restrict__ x,
                                                       const float* __restrict__ alphas,
                                                       const float* __restrict__ coeffs,
                                                       float* __restrict__ out) {
    __shared__ __bf16 wlds[32768];   // 64 KB, B-fragment order

    const int tid  = threadIdx.x;
    const int lane = tid & 63;
    const int wv   = tid >> 6;       // 0..15
    const int m    = lane & 15;      // A row within 16-tile
    const int q    = lane >> 4;      // quad

    // ---- phase A: issue x loads first (HBM latency hides behind phase B) ----
    const int row = blockIdx.x * 256 + wv * 16 + m;
    const float* xp = x + row * 64 + q * 16;
    f32x4 xr0 = *(const f32x4*)(xp + 0);
    f32x4 xr1 = *(const f32x4*)(xp + 4);
    f32x4 xr2 = *(const f32x4*)(xp + 8);
    f32x4 xr3 = *(const f32x4*)(xp + 12);

    // ---- phase B: W2 = softmax(alphas)*coeffs -> LDS (bf16, frag order) -----
    // 4096 units / 1024 threads = 4 each; consecutive tids read consecutive
    // 32B chunks of alphas/coeffs (coalesced, L2/L3-hot after first blocks).
#pragma unroll
    for (int u = 0; u < 4; ++u) {
        const int g = u * 1024 + tid;       // g = i*64 + n
        const int i = g >> 6;
        const int n = g & 63;
        const float* a  = alphas + g * 8;
        const float* cf = coeffs + g * 8;

        float e[8], s = 0.f;
#pragma unroll
        for (int k = 0; k < 8; ++k) {
            e[k] = __builtin_amdgcn_exp2f(a[k] * LOG2E);   // |a|<0.03: no max-sub
            s += e[k];
        }
        const float inv = __builtin_amdgcn_rcpf(s);

        bf16x8 w;
#pragma unroll
        for (int k = 0; k < 8; ++k) w[k] = (__bf16)(e[k] * inv * cf[k]);

        // i = quad*16 + step ; n = tile*16 + nl  -> fragment-order position
        const int qq = i >> 4, cc = i & 15, t = n >> 4, nl = n & 15;
        *(bf16x8*)(wlds + ((cc * 4 + t) * 64 + qq * 16 + nl) * 8) = w;
    }
    __syncthreads();

    // ---- phase C: MFMA main loop -------------------------------------------
    float xa[16];
#pragma unroll
    for (int c = 0; c < 4; ++c) { xa[c] = xr0[c]; xa[4+c] = xr1[c]; xa[8+c] = xr2[c]; xa[12+c] = xr3[c]; }

    f32x4 acc0 = {0.f, 0.f, 0.f, 0.f};
    f32x4 acc1 = {0.f, 0.f, 0.f, 0.f};
    f32x4 acc2 = {0.f, 0.f, 0.f, 0.f};
    f32x4 acc3 = {0.f, 0.f, 0.f, 0.f};

#pragma unroll
    for (int c = 0; c < 16; ++c) {
        const float xv = xa[c];
        const float x2 = xv * xv;
        bf16x8 a;
        a[0] = (__bf16)0.0f;                                        // none
        a[1] = (__bf16)xv;                                          // linear
        a[2] = (__bf16)x2;                                          // x^2
        a[3] = (__bf16)(x2 * xv);                                   // x^3
        a[4] = (__bf16)__builtin_amdgcn_exp2f(xv * LOG2E);          // exp
        a[5] = (__bf16)(__builtin_amdgcn_logf(xv) * LN2);           // ln
        a[6] = (__bf16)__builtin_amdgcn_rcpf(xv);                   // 1/x
        a[7] = (__bf16)__builtin_amdgcn_sinf(xv * INV2PI);          // sin
        const __bf16* bb = wlds + c * 2048 + lane * 8;
        bf16x8 b0 = *(const bf16x8*)(bb);
        bf16x8 b1 = *(const bf16x8*)(bb + 512);
        bf16x8 b2 = *(const bf16x8*)(bb + 1024);
        bf16x8 b3 = *(const bf16x8*)(bb + 1536);
        acc0 = __builtin_amdgcn_mfma_f32_16x16x32_bf16(a, b0, acc0, 0, 0, 0);
        acc1 = __builtin_amdgcn_mfma_f32_16x16x32_bf16(a, b1, acc1, 0, 0, 0);
        acc2 = __builtin_amdgcn_mfma_f32_16x16x32_bf16(a, b2, acc2, 0, 0, 0);
        acc3 = __builtin_amdgcn_mfma_f32_16x16x32_bf16(a, b3, acc3, 0, 0, 0);
    }

    // ---- epilogue: C layout col=lane&15, row=q*4+r -------------------------
    float* orow = out + (blockIdx.x * 256 + wv * 16 + q * 4) * 64 + m;
#pragma unroll
    for (int r = 0; r < 4; ++r) {
        orow[r * 64 + 0]  = acc0[r];
        orow[r * 64 + 16] = acc1[r];
        orow[r * 64 + 32] = acc2[r];
        orow[r * 64 + 48] = acc3[r];
    }
}

extern "C" void kernel_launch(void* const* d_in, const int* in_sizes, int n_in,
                              void* d_out, int out_size, void* d_ws, size_t ws_size,
                              hipStream_t stream) {
    const float* x      = (const float*)d_in[0];
    const float* alphas = (const float*)d_in[1];
    const float* coeffs = (const float*)d_in[2];
    float* out = (float*)d_out;
    (void)d_ws; (void)ws_size;

    darts_fused<<<256, 1024, 0, stream>>>(x, alphas, coeffs, out);
}